// Round 10
// baseline (294.370 us; speedup 1.0000x reference)
//
#include <hip/hip_runtime.h>

#define BB 2
#define NN 2048
#define DD 1024
#define HH 16
#define HD 64
#define RR (BB * NN)  // 4096 rows
#define CT 32         // chunk length (steps)
#define NC (NN / CT)  // 64 chunks per (b,h)

typedef __bf16 bf16x8 __attribute__((ext_vector_type(8)));
typedef __bf16 bf16x4 __attribute__((ext_vector_type(4)));
typedef float f32x4 __attribute__((ext_vector_type(4)));
typedef float f32x2 __attribute__((ext_vector_type(2)));

__device__ __forceinline__ float sigmoidf_(float x) { return 1.f / (1.f + __expf(-x)); }

#define MFMA16(a, b, c) __builtin_amdgcn_mfma_f32_16x16x32_bf16((a), (b), (c), 0, 0, 0)

// async global -> LDS DMA (gfx950). LDS dst is wave-uniform; lane i's data
// lands at dst + i*size. Global src is a normal per-lane address.
__device__ __forceinline__ void gl2lds16(const void* g, void* l) {
    __builtin_amdgcn_global_load_lds((const __attribute__((address_space(1))) void*)g,
                                     (__attribute__((address_space(3))) void*)l, 16, 0, 0);
}

// ---------------------------------------------------------------------------
// x (f32) -> bf16, 8 elems/thread.
// ---------------------------------------------------------------------------
__global__ __launch_bounds__(256) void xcvt(const float* __restrict__ x,
                                            __bf16* __restrict__ xb) {
    const size_t i = ((size_t)blockIdx.x * 256 + threadIdx.x) * 8;
    float4 a = *(const float4*)(x + i);
    float4 b = *(const float4*)(x + i + 4);
    bf16x8 o;
    o[0] = (__bf16)a.x; o[1] = (__bf16)a.y; o[2] = (__bf16)a.z; o[3] = (__bf16)a.w;
    o[4] = (__bf16)b.x; o[5] = (__bf16)b.y; o[6] = (__bf16)b.z; o[7] = (__bf16)b.w;
    *(bf16x8*)(xb + i) = o;
}

// ---------------------------------------------------------------------------
// Weight transpose+convert: S (f32, [K][N]) -> D (bf16, [N][K]). (unchanged)
// ---------------------------------------------------------------------------
__global__ __launch_bounds__(256) void wtrans(const float* S0, const float* S1,
                                              const float* S2, const float* S3,
                                              __bf16* D0, __bf16* D1,
                                              __bf16* D2, __bf16* D3,
                                              int K, int N) {
    __shared__ float t[64][65];
    const int z = blockIdx.z;
    const float* S = (z == 0) ? S0 : ((z == 1) ? S1 : ((z == 2) ? S2 : S3));
    __bf16* D = (z == 0) ? D0 : ((z == 1) ? D1 : ((z == 2) ? D2 : D3));
    const int tid = threadIdx.x;
    const int ti = blockIdx.y * 64;  // k tile
    const int tj = blockIdx.x * 64;  // n tile
    const int r = tid >> 2, c0 = (tid & 3) * 16;
    const float* sp = S + (size_t)(ti + r) * N + tj + c0;
#pragma unroll
    for (int p = 0; p < 4; p++) {
        float4 v = *(const float4*)(sp + 4 * p);
        t[r][c0 + 4 * p + 0] = v.x; t[r][c0 + 4 * p + 1] = v.y;
        t[r][c0 + 4 * p + 2] = v.z; t[r][c0 + 4 * p + 3] = v.w;
    }
    __syncthreads();
    bf16x8 o0, o1;
#pragma unroll
    for (int j = 0; j < 8; j++) o0[j] = (__bf16)t[c0 + j][r];
#pragma unroll
    for (int j = 0; j < 8; j++) o1[j] = (__bf16)t[c0 + 8 + j][r];
    __bf16* dp = D + (size_t)(tj + r) * K + ti + c0;
    *(bf16x8*)dp = o0;
    *(bf16x8*)(dp + 8) = o1;
}

// ---------------------------------------------------------------------------
// W96T[c][k] (bf16, 128x1024, zero-padded rows 96..127) = [Wgamma|Wf|Wg1]^T.
// ---------------------------------------------------------------------------
__global__ __launch_bounds__(256) void wtrans96(const float* __restrict__ Wgm,
                                                const float* __restrict__ Wf,
                                                const float* __restrict__ Wg1,
                                                __bf16* __restrict__ W96T) {
    const int c = blockIdx.x;        // 0..127
    const int k0 = threadIdx.x * 4;  // 0..1020
    bf16x4 o;
    if (c < 96) {
        const float* src;
        int stride;
        if (c < 16)      { src = Wgm + c;        stride = 16; }
        else if (c < 32) { src = Wf + (c - 16);  stride = 16; }
        else             { src = Wg1 + (c - 32); stride = 64; }
#pragma unroll
        for (int j = 0; j < 4; j++) o[j] = (__bf16)src[(size_t)(k0 + j) * stride];
    } else {
        o[0] = o[1] = o[2] = o[3] = (__bf16)0.f;
    }
    *(bf16x4*)(W96T + (size_t)c * 1024 + k0) = o;
}

// ---------------------------------------------------------------------------
// bf16 GEMM, m97 structure + single-buffer DMA prefetch (round-8 verified)
// + XCD-aware bijective block swizzle (all grids have nwg % 8 == 0): each
// XCD gets a contiguous flat range -> A row-band reuse in its private L2.
// ---------------------------------------------------------------------------
__global__ __launch_bounds__(256) void gemm_bt(const __bf16* __restrict__ A,
                                               const __bf16* B0, const __bf16* B1,
                                               const __bf16* B2, const __bf16* B3,
                                               float* C0, float* C1, float* C2, float* C3,
                                               int M, int N, int K) {
    constexpr int BK = 32;
    __shared__ __align__(16) __bf16 As[128 * BK];
    __shared__ __align__(16) __bf16 Bs[128 * BK];
    const int nwg = (int)(gridDim.x * gridDim.y);
    const int flat = (int)(blockIdx.y * gridDim.x + blockIdx.x);
    const int swz = (flat & 7) * (nwg >> 3) + (flat >> 3);
    const int bxs = swz % (int)gridDim.x, bys = swz / (int)gridDim.x;
    const int mat = bxs >> 3;
    const __bf16* B = (mat == 0) ? B0 : ((mat == 1) ? B1 : ((mat == 2) ? B2 : B3));
    float* C = (mat == 0) ? C0 : ((mat == 1) ? C1 : ((mat == 2) ? C2 : C3));
    const int Nn = (mat == 3) ? 128 : N;
    const int tid = threadIdx.x;
    const int lane = tid & 63;
    const int wave = tid >> 6;
    const int wm = (wave >> 1) * 64, wn = (wave & 1) * 64;
    const int bm = bys * 128, bn = (bxs & 7) * 128;
    const int l15 = lane & 15, quad = lane >> 4;

    const int srow = lane >> 2, scol = (lane & 3) * 8;
    const __bf16* gA = A + (size_t)(bm + wave * 16 + srow) * K + scol;
    const __bf16* gB = B + (size_t)(bn + wave * 16 + srow) * K + scol;
    const size_t rstep = (size_t)64 * K;
    __bf16* lA0 = &As[(wave * 16) * BK];
    __bf16* lA1 = &As[(wave * 16 + 64) * BK];
    __bf16* lB0 = &Bs[(wave * 16) * BK];
    __bf16* lB1 = &Bs[(wave * 16 + 64) * BK];

    f32x4 acc[4][4];
#pragma unroll
    for (int i = 0; i < 4; i++)
#pragma unroll
        for (int j = 0; j < 4; j++) acc[i][j] = (f32x4){0.f, 0.f, 0.f, 0.f};

    // prologue: DMA tile 0
    gl2lds16(gA, lA0);
    gl2lds16(gA + rstep, lA1);
    gl2lds16(gB, lB0);
    gl2lds16(gB + rstep, lB1);

    for (int kb = 0; kb < K; kb += BK) {
        asm volatile("s_waitcnt vmcnt(0)" ::: "memory");
        __syncthreads();  // tile kb landed in LDS (all waves)

        bf16x8 af[4], bfr[4];
#pragma unroll
        for (int i = 0; i < 4; i++)
            af[i] = *(const bf16x8*)&As[(wm + i * 16 + l15) * BK + quad * 8];
#pragma unroll
        for (int j = 0; j < 4; j++)
            bfr[j] = *(const bf16x8*)&Bs[(wn + j * 16 + l15) * BK + quad * 8];
        __syncthreads();  // all waves' frag reads drained -> LDS reusable

        if (kb + BK < K) {  // issue next tile's DMA; overlaps MFMA below
            gl2lds16(gA + kb + BK, lA0);
            gl2lds16(gA + kb + BK + rstep, lA1);
            gl2lds16(gB + kb + BK, lB0);
            gl2lds16(gB + kb + BK + rstep, lB1);
        }
        __builtin_amdgcn_sched_barrier(0);  // pin DMA issue before MFMA cluster

#pragma unroll
        for (int i = 0; i < 4; i++)
#pragma unroll
            for (int j = 0; j < 4; j++)
                acc[i][j] = MFMA16(af[i], bfr[j], acc[i][j]);
    }

#pragma unroll
    for (int i = 0; i < 4; i++) {
#pragma unroll
        for (int r = 0; r < 4; r++) {
            const int row = bm + wm + i * 16 + quad * 4 + r;
            float* cp = C + (size_t)row * Nn + bn + wn + l15;
#pragma unroll
            for (int j = 0; j < 4; j++) cp[j * 16] = acc[i][j][r];
        }
    }
}

// ---------------------------------------------------------------------------
// Tiny per-head scalars + g1 bf16 conversion from c96. (unchanged)
// ---------------------------------------------------------------------------
__global__ __launch_bounds__(256) void scal_prep(const float* __restrict__ c96,
                                                 float* __restrict__ lfb,
                                                 float* __restrict__ csb,
                                                 __bf16* __restrict__ g1b) {
    const int tid = threadIdx.x;
    const int row = blockIdx.x * 16 + (tid >> 4);
    const int h = tid & 15;
    const float* cr = c96 + (size_t)row * 128;
    const float sig = sigmoidf_(cr[16 + h]);       // lambda
    const float gm = -sigmoidf_(cr[h]);            // gamma
    lfb[(size_t)row * HH + h] = sig;
    csb[(size_t)row * HH + h] = gm * sig * sig;
    const int c4 = h * 4;
    bf16x4 o;
    o[0] = (__bf16)cr[32 + c4 + 0]; o[1] = (__bf16)cr[32 + c4 + 1];
    o[2] = (__bf16)cr[32 + c4 + 2]; o[3] = (__bf16)cr[32 + c4 + 3];
    *(bf16x4*)(g1b + (size_t)row * 64 + c4) = o;
}

// ---------------------------------------------------------------------------
// Chunked delta-rule, phase 1 — raw q/k, silu + k-l2norm in-block. (unchanged
// round 8/9 — verified)
// ---------------------------------------------------------------------------
__global__ __launch_bounds__(64) void chunk_prep(const float* __restrict__ qb,
                                                 const float* __restrict__ kb,
                                                 const float* __restrict__ lfb,
                                                 const float* __restrict__ csb,
                                                 __bf16* __restrict__ ck_hat,
                                                 __bf16* __restrict__ ck_q,
                                                 __bf16* __restrict__ ck_kbT,
                                                 __bf16* __restrict__ ck_M,
                                                 __bf16* __restrict__ ck_G,
                                                 float* __restrict__ ck_lam) {
    __shared__ __align__(16) __bf16 khL[32][72];
    __shared__ __align__(16) __bf16 kbL[32][72];
    __shared__ __align__(16) __bf16 qtL[32][72];
    __shared__ float Afp[32][33];
    __shared__ float scl[3][32];
    const int bx = blockIdx.x;
    const int bh = bx >> 6, ci = bx & 63;
    const int b = bh >> 4, h = bh & 15;
    const int l = threadIdx.x;
    const int l15 = l & 15, quad = l >> 4, t32 = l & 31;
    const size_t cid = (size_t)bh * NC + ci;

    const size_t mb = ((size_t)(b * NN + ci * CT) + t32) * HH + h;
    float c_t = csb[mb];
    float p = lfb[mb];
#pragma unroll
    for (int d = 1; d <= 16; d <<= 1) {
        float o = __shfl_up(p, d);
        p *= (t32 >= d) ? o : 1.f;
    }
    float pm1 = __shfl_up(p, 1);
    if (t32 == 0) pm1 = 1.f;
    const float lamT = __shfl(p, 31);
    if (l < 32) {
        scl[0][t32] = c_t * pm1;  // khat scale
        scl[1][t32] = 1.f / p;    // kbar scale
        scl[2][t32] = p;          // qtil scale
    }
    if (l == 0) ck_lam[cid] = lamT;
    __syncthreads();

    const size_t rb0 = ((size_t)(b * NN + ci * CT)) * DD + h * HD;
    __bf16* khG = ck_hat + cid * 2048;
    __bf16* qtG = ck_q + cid * 2048;
    __bf16* kTG = ck_kbT + cid * 2048;
#pragma unroll
    for (int rep = 0; rep < 8; rep++) {
        const int row = rep * 4 + quad;
        const int c4 = l15 * 4;
        float4 kv = *(const float4*)(kb + rb0 + (size_t)row * DD + c4);
        float4 qv = *(const float4*)(qb + rb0 + (size_t)row * DD + c4);
        // silu
        kv.x *= sigmoidf_(kv.x); kv.y *= sigmoidf_(kv.y);
        kv.z *= sigmoidf_(kv.z); kv.w *= sigmoidf_(kv.w);
        qv.x *= sigmoidf_(qv.x); qv.y *= sigmoidf_(qv.y);
        qv.z *= sigmoidf_(qv.z); qv.w *= sigmoidf_(qv.w);
        // l2 norm of silu'd k over the row (16 lanes x 4 elems = 64 d)
        float ss = kv.x * kv.x + kv.y * kv.y + kv.z * kv.z + kv.w * kv.w;
        ss += __shfl_xor(ss, 1); ss += __shfl_xor(ss, 2);
        ss += __shfl_xor(ss, 4); ss += __shfl_xor(ss, 8);
        const float inv = 1.f / fmaxf(sqrtf(ss), 1e-12f);
        const float sh = scl[0][row] * inv, sbr = scl[1][row] * inv, sq = scl[2][row];
        bf16x4 khv, kbv, qtv;
        khv[0] = (__bf16)(kv.x * sh); khv[1] = (__bf16)(kv.y * sh);
        khv[2] = (__bf16)(kv.z * sh); khv[3] = (__bf16)(kv.w * sh);
        kbv[0] = (__bf16)(kv.x * sbr); kbv[1] = (__bf16)(kv.y * sbr);
        kbv[2] = (__bf16)(kv.z * sbr); kbv[3] = (__bf16)(kv.w * sbr);
        qtv[0] = (__bf16)(qv.x * sq); qtv[1] = (__bf16)(qv.y * sq);
        qtv[2] = (__bf16)(qv.z * sq); qtv[3] = (__bf16)(qv.w * sq);
        *(bf16x4*)&khL[row][c4] = khv;
        *(bf16x4*)&kbL[row][c4] = kbv;
        *(bf16x4*)&qtL[row][c4] = qtv;
        *(bf16x4*)(khG + row * 64 + c4) = khv;
        *(bf16x4*)(qtG + row * 64 + c4) = qtv;
#pragma unroll
        for (int j = 0; j < 4; j++) kTG[(c4 + j) * 32 + row] = kbv[j];
    }
    __syncthreads();

    __bf16* GG = ck_G + cid * 1024;
#pragma unroll
    for (int mi = 0; mi < 2; mi++)
#pragma unroll
        for (int ni = 0; ni < 2; ni++) {
            f32x4 aA = (f32x4){0.f, 0.f, 0.f, 0.f};
            f32x4 aG = (f32x4){0.f, 0.f, 0.f, 0.f};
#pragma unroll
            for (int k2 = 0; k2 < 2; k2++) {
                bf16x8 bfr = *(const bf16x8*)&kbL[ni * 16 + l15][k2 * 32 + quad * 8];
                bf16x8 afr = *(const bf16x8*)&khL[mi * 16 + l15][k2 * 32 + quad * 8];
                bf16x8 qfr = *(const bf16x8*)&qtL[mi * 16 + l15][k2 * 32 + quad * 8];
                aA = MFMA16(afr, bfr, aA);
                aG = MFMA16(qfr, bfr, aG);
            }
#pragma unroll
            for (int r = 0; r < 4; r++) {
                const int row = mi * 16 + quad * 4 + r, col = ni * 16 + l15;
                Afp[row][col] = (col < row) ? aA[r] : 0.f;
                GG[row * 32 + col] = (__bf16)((col <= row) ? aG[r] : 0.f);
            }
        }
    __syncthreads();

    __bf16* MG = ck_M + cid * 1024;
    if (l < 32) {
        float m[32];
#pragma unroll
        for (int t = 0; t < 32; t++) {
            float r = (l == t) ? 1.f : 0.f;
#pragma unroll
            for (int s = 0; s < t; s++) r += Afp[t][s] * m[s];
            m[t] = r;
            MG[t * 32 + l] = (__bf16)r;
        }
    }
}

// ---------------------------------------------------------------------------
// Chunked delta-rule, phase 2 — PAIRED v-slices: one wave handles the two
// 16-col slices of a (bh, pair) that share ALL chunk factors (same cid), so
// one FragSet serves both (halves ck_* fetch) and the two independent
// compute chains interleave to hide LDS round-trip + MFMA-dep latency.
// 64 blocks x 64 threads. v raw; silu applied in compute (round-9 lesson).
// ---------------------------------------------------------------------------
struct FragSet {
    bf16x8 ka[2][2], qa[2][2], ma[2], ga[2], kba[4];
    f32x4 vv[2][2];  // [slice][mi]
    float lam;
};

__global__ __launch_bounds__(64) void chunk_scan(const __bf16* __restrict__ ck_hat,
                                                 const __bf16* __restrict__ ck_q,
                                                 const __bf16* __restrict__ ck_kbT,
                                                 const __bf16* __restrict__ ck_M,
                                                 const __bf16* __restrict__ ck_G,
                                                 const float* __restrict__ ck_lam,
                                                 const float* __restrict__ vb,
                                                 __bf16* __restrict__ obh) {
    __shared__ __align__(16) __bf16 Sbt[2][16][72];
    __shared__ __align__(16) __bf16 Vbt[2][16][40];
    __shared__ __align__(16) __bf16 Ubt[2][16][40];
    const int bx = blockIdx.x;              // 64 blocks
    const int bh = bx >> 1, pp = bx & 1;    // pair pp covers vs = 2pp, 2pp+1
    const int b = bh >> 4, h = bh & 15;
    const int l = threadIdx.x, l15 = l & 15, quad = l >> 4;
    const size_t cid0 = (size_t)bh * NC;
    const size_t vcol[2] = {(size_t)h * HD + (size_t)(pp * 2) * 16 + l15,
                            (size_t)h * HD + (size_t)(pp * 2 + 1) * 16 + l15};
    const size_t rowb = (size_t)b * NN;

    f32x4 S[2][4];
#pragma unroll
    for (int s = 0; s < 2; s++)
#pragma unroll
        for (int dt = 0; dt < 4; dt++) S[s][dt] = (f32x4){0.f, 0.f, 0.f, 0.f};

    auto load = [&](FragSet& f, int ci) {
        const __bf16* khp = ck_hat + (cid0 + ci) * 2048;
        const __bf16* qp = ck_q + (cid0 + ci) * 2048;
        const __bf16* kTp = ck_kbT + (cid0 + ci) * 2048;
        const __bf16* Mp = ck_M + (cid0 + ci) * 1024;
        const __bf16* Gp = ck_G + (cid0 + ci) * 1024;
#pragma unroll
        for (int mi = 0; mi < 2; mi++) {
#pragma unroll
            for (int k2 = 0; k2 < 2; k2++) {
                f.ka[mi][k2] = *(const bf16x8*)(khp + (mi * 16 + l15) * 64 + k2 * 32 + quad * 8);
                f.qa[mi][k2] = *(const bf16x8*)(qp + (mi * 16 + l15) * 64 + k2 * 32 + quad * 8);
            }
            f.ma[mi] = *(const bf16x8*)(Mp + (mi * 16 + l15) * 32 + quad * 8);
            f.ga[mi] = *(const bf16x8*)(Gp + (mi * 16 + l15) * 32 + quad * 8);
        }
#pragma unroll
        for (int dt = 0; dt < 4; dt++)
            f.kba[dt] = *(const bf16x8*)(kTp + (dt * 16 + l15) * 32 + quad * 8);
        // RAW v for both slices — no dependent VALU here (waitcnt stays deferred)
#pragma unroll
        for (int s = 0; s < 2; s++)
#pragma unroll
            for (int mi = 0; mi < 2; mi++)
#pragma unroll
                for (int r = 0; r < 4; r++)
                    f.vv[s][mi][r] =
                        vb[(rowb + ci * CT + mi * 16 + quad * 4 + r) * DD + vcol[s]];
        f.lam = ck_lam[cid0 + ci];
    };

    auto compute = [&](const FragSet& f, int ci) {
        const f32x4 z = (f32x4){0.f, 0.f, 0.f, 0.f};
        // S -> Sbt (bf16) for both slices
#pragma unroll
        for (int s = 0; s < 2; s++)
#pragma unroll
            for (int dt = 0; dt < 4; dt++) {
                bf16x4 t;
#pragma unroll
                for (int r = 0; r < 4; r++) t[r] = (__bf16)S[s][dt][r];
                *(bf16x4*)&Sbt[s][l15][dt * 16 + quad * 4] = t;
            }
        bf16x8 sb0[2], sb1[2];
#pragma unroll
        for (int s = 0; s < 2; s++) {
            sb0[s] = *(const bf16x8*)&Sbt[s][l15][quad * 8];
            sb1[s] = *(const bf16x8*)&Sbt[s][l15][32 + quad * 8];
        }
        // P = Khat @ S0 ; += silu(v)
        f32x4 p0[2], p1[2];
#pragma unroll
        for (int s = 0; s < 2; s++) {
            p0[s] = MFMA16(f.ka[0][0], sb0[s], z); p0[s] = MFMA16(f.ka[0][1], sb1[s], p0[s]);
            p1[s] = MFMA16(f.ka[1][0], sb0[s], z); p1[s] = MFMA16(f.ka[1][1], sb1[s], p1[s]);
        }
#pragma unroll
        for (int s = 0; s < 2; s++)
#pragma unroll
            for (int r = 0; r < 4; r++) {
                const float v0 = f.vv[s][0][r], v1 = f.vv[s][1][r];
                p0[s][r] += v0 * sigmoidf_(v0);
                p1[s][r] += v1 * sigmoidf_(v1);
            }
#pragma unroll
        for (int s = 0; s < 2; s++) {
            bf16x4 t0, t1;
#pragma unroll
            for (int r = 0; r < 4; r++) { t0[r] = (__bf16)p0[s][r]; t1[r] = (__bf16)p1[s][r]; }
            *(bf16x4*)&Vbt[s][l15][quad * 4] = t0;
            *(bf16x4*)&Vbt[s][l15][16 + quad * 4] = t1;
        }
        bf16x8 vfr[2];
#pragma unroll
        for (int s = 0; s < 2; s++) vfr[s] = *(const bf16x8*)&Vbt[s][l15][quad * 8];
        // U = M @ V''
        f32x4 u0[2], u1[2];
#pragma unroll
        for (int s = 0; s < 2; s++) {
            u0[s] = MFMA16(f.ma[0], vfr[s], z);
            u1[s] = MFMA16(f.ma[1], vfr[s], z);
        }
#pragma unroll
        for (int s = 0; s < 2; s++) {
            bf16x4 t0, t1;
#pragma unroll
            for (int r = 0; r < 4; r++) { t0[r] = (__bf16)u0[s][r]; t1[r] = (__bf16)u1[s][r]; }
            *(bf16x4*)&Ubt[s][l15][quad * 4] = t0;
            *(bf16x4*)&Ubt[s][l15][16 + quad * 4] = t1;
        }
        bf16x8 ufr[2];
#pragma unroll
        for (int s = 0; s < 2; s++) ufr[s] = *(const bf16x8*)&Ubt[s][l15][quad * 8];
        // O = Qtil @ S0 + G @ U
#pragma unroll
        for (int s = 0; s < 2; s++) {
            f32x4 o0 = MFMA16(f.qa[0][0], sb0[s], z); o0 = MFMA16(f.qa[0][1], sb1[s], o0);
            o0 = MFMA16(f.ga[0], ufr[s], o0);
            f32x4 o1 = MFMA16(f.qa[1][0], sb0[s], z); o1 = MFMA16(f.qa[1][1], sb1[s], o1);
            o1 = MFMA16(f.ga[1], ufr[s], o1);
#pragma unroll
            for (int r = 0; r < 4; r++) {
                obh[(rowb + ci * CT + quad * 4 + r) * DD + vcol[s]] = (__bf16)o0[r];
                obh[(rowb + ci * CT + 16 + quad * 4 + r) * DD + vcol[s]] = (__bf16)o1[r];
            }
        }
        // S = LamT * (S0 + KbarT @ U)
#pragma unroll
        for (int s = 0; s < 2; s++)
#pragma unroll
            for (int dt = 0; dt < 4; dt++) {
                S[s][dt] = MFMA16(f.kba[dt], ufr[s], S[s][dt]);
#pragma unroll
                for (int r = 0; r < 4; r++) S[s][dt][r] *= f.lam;
            }
    };

    FragSet fA, fB;
    load(fA, 0);
    for (int ci = 0; ci < NC; ci += 2) {
        load(fB, ci + 1);
        __builtin_amdgcn_sched_barrier(0);
        compute(fA, ci);
        load(fA, (ci + 2 < NC) ? ci + 2 : NC - 1);
        __builtin_amdgcn_sched_barrier(0);
        compute(fB, ci + 1);
    }
}

// ---------------------------------------------------------------------------
// lnob = bf16( LayerNorm(o * sigmoid(gatep)) * norm_w ). (unchanged)
// ---------------------------------------------------------------------------
__global__ __launch_bounds__(256) void gate_ln_kernel(const __bf16* __restrict__ obh,
                                                      const float* __restrict__ gatep,
                                                      const float* __restrict__ nw,
                                                      __bf16* __restrict__ lnob) {
    const int r = blockIdx.x, tid = threadIdx.x;
    const int wav = tid >> 6, lane = tid & 63;
    __shared__ float red[8];
    const size_t rb = (size_t)r * DD;

    float vals[4];
    float s = 0.f;
#pragma unroll
    for (int p = 0; p < 4; p++) {
        const int j = tid + 256 * p;
        float xg = (float)obh[rb + j] * sigmoidf_(gatep[rb + j]);
        vals[p] = xg;
        s += xg;
    }
#pragma unroll
    for (int m = 1; m <= 32; m <<= 1) s += __shfl_xor(s, m);
    if (lane == 0) red[wav] = s;
    __syncthreads();
    const float mu = (red[0] + red[1] + red[2] + red[3]) * (1.f / 1024.f);

    float s2 = 0.f;
#pragma unroll
    for (int p = 0; p < 4; p++) { float d = vals[p] - mu; s2 += d * d; }
#pragma unroll
    for (int m = 1; m <= 32; m <<= 1) s2 += __shfl_xor(s2, m);
    if (lane == 0) red[4 + wav] = s2;
    __syncthreads();
    const float var = (red[4] + red[5] + red[6] + red[7]) * (1.f / 1024.f);
    const float rs = rsqrtf(var + 1e-5f);

#pragma unroll
    for (int p = 0; p < 4; p++) {
        const int j = tid + 256 * p;
        lnob[rb + j] = (__bf16)((vals[p] - mu) * rs * nw[j]);
    }
}

// ---------------------------------------------------------------------------
extern "C" void kernel_launch(void* const* d_in, const int* in_sizes, int n_in,
                              void* d_out, int out_size, void* d_ws, size_t ws_size,
                              hipStream_t stream) {
    const float* x   = (const float*)d_in[0];
    const float* Wq  = (const float*)d_in[1];
    const float* Wk  = (const float*)d_in[2];
    const float* Wv  = (const float*)d_in[3];
    const float* Wgm = (const float*)d_in[4];  // Wgamma
    const float* Wf  = (const float*)d_in[5];
    const float* Wg1 = (const float*)d_in[6];
    const float* Wg2 = (const float*)d_in[7];
    const float* Wo  = (const float*)d_in[8];
    const float* nw  = (const float*)d_in[9];
    float* out = (float*)d_out;

    float* w = (float*)d_ws;
    float* qb    = w;                     // 4096x1024 f32 raw q (later lnob bf16)
    float* kb    = qb + 4194304;          // raw k
    float* vb    = kb + 4194304;          // raw v
    float* gatep = vb + 4194304;
    __bf16* g1b  = (__bf16*)(gatep + 4194304);  // 4096x64 bf16
    float* lfb   = gatep + 4194304 + 131072;    // 4096x16 (lambda)
    float* csb   = lfb + 65536;                 // 4096x16 (gamma*lambda^2)
    __bf16* obh  = (__bf16*)(csb + 65536);      // 4096x1024 bf16 scan output
    float* cw    = csb + 65536 + 2097152;       // chunk workspace
    __bf16* ck_hat = (__bf16*)cw;               // [2048][32][64] bf16
    __bf16* ck_q   = (__bf16*)(cw + 2097152);   // [2048][32][64]
    __bf16* ck_kbT = (__bf16*)(cw + 4194304);   // [2048][64][32]
    __bf16* ck_M   = (__bf16*)(cw + 6291456);   // [2048][32][32]
    __bf16* ck_G   = (__bf16*)(cw + 7340032);   // [2048][32][32]
    float*  ck_lam = cw + 8388608;              // [2048]
    float* nw2   = cw + 8390656;
    __bf16* xb   = (__bf16*)nw2;                // 4096x1024 bf16
    __bf16* WqT  = (__bf16*)(nw2 + 2097152);    // 1024x1024 bf16 (transposed)
    __bf16* WkT  = (__bf16*)(nw2 + 2621440);
    __bf16* WvT  = (__bf16*)(nw2 + 3145728);
    __bf16* WoT  = (__bf16*)(nw2 + 3670016);
    __bf16* Wg2T = (__bf16*)(nw2 + 4194304);    // 1024x64 bf16
    __bf16* W96T = (__bf16*)(nw2 + 4227072);    // 128x1024 bf16 (padded)
    float* c96   = nw2 + 4292608;               // 4096x128 f32
    __bf16* lnob = (__bf16*)qb;                 // reuse qb

    dim3 blk(256);
    xcvt<<<2048, blk, 0, stream>>>(x, xb);
    wtrans<<<dim3(16, 16, 4), blk, 0, stream>>>(Wq, Wk, Wv, Wo, WqT, WkT, WvT, WoT,
                                                DD, DD);
    wtrans<<<dim3(16, 1, 1), blk, 0, stream>>>(Wg2, Wg2, Wg2, Wg2, Wg2T, Wg2T, Wg2T,
                                               Wg2T, HD, DD);
    wtrans96<<<128, blk, 0, stream>>>(Wgm, Wf, Wg1, W96T);
    // fused q,k,v + 96-col proj: 25 x-blocks = 3x8 col-tiles + 1 (mat 3, N=128)
    gemm_bt<<<dim3(25, 32), blk, 0, stream>>>(xb, WqT, WkT, WvT, W96T,
                                              qb, kb, vb, c96, RR, DD, DD);
    scal_prep<<<RR / 16, blk, 0, stream>>>(c96, lfb, csb, g1b);
    gemm_bt<<<dim3(8, 32), blk, 0, stream>>>(g1b, Wg2T, Wg2T, Wg2T, Wg2T,
                                             gatep, gatep, gatep, gatep, RR, DD, HD);
    chunk_prep<<<32 * NC, 64, 0, stream>>>(qb, kb, lfb, csb,
                                           ck_hat, ck_q, ck_kbT, ck_M, ck_G, ck_lam);
    chunk_scan<<<64, 64, 0, stream>>>(ck_hat, ck_q, ck_kbT, ck_M, ck_G, ck_lam, vb, obh);
    gate_ln_kernel<<<RR, blk, 0, stream>>>(obh, gatep, nw, lnob);
    gemm_bt<<<dim3(8, 32), blk, 0, stream>>>(lnob, WoT, WoT, WoT, WoT,
                                             out, out, out, out, RR, DD, DD);
}

// Round 11
// 257.745 us; speedup vs baseline: 1.1421x; 1.1421x over previous
//
#include <hip/hip_runtime.h>

#define BB 2
#define NN 2048
#define DD 1024
#define HH 16
#define HD 64
#define RR (BB * NN)  // 4096 rows
#define CT 32         // chunk length (steps)
#define NC (NN / CT)  // 64 chunks per (b,h)

typedef __bf16 bf16x8 __attribute__((ext_vector_type(8)));
typedef __bf16 bf16x4 __attribute__((ext_vector_type(4)));
typedef float f32x4 __attribute__((ext_vector_type(4)));
typedef float f32x2 __attribute__((ext_vector_type(2)));

__device__ __forceinline__ float sigmoidf_(float x) { return 1.f / (1.f + __expf(-x)); }

#define MFMA16(a, b, c) __builtin_amdgcn_mfma_f32_16x16x32_bf16((a), (b), (c), 0, 0, 0)

// async global -> LDS DMA (gfx950). LDS dst is wave-uniform; lane i's data
// lands at dst + i*size. Global src is a normal per-lane address.
__device__ __forceinline__ void gl2lds16(const void* g, void* l) {
    __builtin_amdgcn_global_load_lds((const __attribute__((address_space(1))) void*)g,
                                     (__attribute__((address_space(3))) void*)l, 16, 0, 0);
}

// ---------------------------------------------------------------------------
// x (f32) -> bf16, 8 elems/thread.
// ---------------------------------------------------------------------------
__global__ __launch_bounds__(256) void xcvt(const float* __restrict__ x,
                                            __bf16* __restrict__ xb) {
    const size_t i = ((size_t)blockIdx.x * 256 + threadIdx.x) * 8;
    float4 a = *(const float4*)(x + i);
    float4 b = *(const float4*)(x + i + 4);
    bf16x8 o;
    o[0] = (__bf16)a.x; o[1] = (__bf16)a.y; o[2] = (__bf16)a.z; o[3] = (__bf16)a.w;
    o[4] = (__bf16)b.x; o[5] = (__bf16)b.y; o[6] = (__bf16)b.z; o[7] = (__bf16)b.w;
    *(bf16x8*)(xb + i) = o;
}

// ---------------------------------------------------------------------------
// Weight transpose+convert: S (f32, [K][N]) -> D (bf16, [N][K]). (unchanged)
// ---------------------------------------------------------------------------
__global__ __launch_bounds__(256) void wtrans(const float* S0, const float* S1,
                                              const float* S2, const float* S3,
                                              __bf16* D0, __bf16* D1,
                                              __bf16* D2, __bf16* D3,
                                              int K, int N) {
    __shared__ float t[64][65];
    const int z = blockIdx.z;
    const float* S = (z == 0) ? S0 : ((z == 1) ? S1 : ((z == 2) ? S2 : S3));
    __bf16* D = (z == 0) ? D0 : ((z == 1) ? D1 : ((z == 2) ? D2 : D3));
    const int tid = threadIdx.x;
    const int ti = blockIdx.y * 64;  // k tile
    const int tj = blockIdx.x * 64;  // n tile
    const int r = tid >> 2, c0 = (tid & 3) * 16;
    const float* sp = S + (size_t)(ti + r) * N + tj + c0;
#pragma unroll
    for (int p = 0; p < 4; p++) {
        float4 v = *(const float4*)(sp + 4 * p);
        t[r][c0 + 4 * p + 0] = v.x; t[r][c0 + 4 * p + 1] = v.y;
        t[r][c0 + 4 * p + 2] = v.z; t[r][c0 + 4 * p + 3] = v.w;
    }
    __syncthreads();
    bf16x8 o0, o1;
#pragma unroll
    for (int j = 0; j < 8; j++) o0[j] = (__bf16)t[c0 + j][r];
#pragma unroll
    for (int j = 0; j < 8; j++) o1[j] = (__bf16)t[c0 + 8 + j][r];
    __bf16* dp = D + (size_t)(tj + r) * K + ti + c0;
    *(bf16x8*)dp = o0;
    *(bf16x8*)(dp + 8) = o1;
}

// ---------------------------------------------------------------------------
// W96T[c][k] (bf16, 128x1024, zero-padded rows 96..127) = [Wgamma|Wf|Wg1]^T.
// ---------------------------------------------------------------------------
__global__ __launch_bounds__(256) void wtrans96(const float* __restrict__ Wgm,
                                                const float* __restrict__ Wf,
                                                const float* __restrict__ Wg1,
                                                __bf16* __restrict__ W96T) {
    const int c = blockIdx.x;        // 0..127
    const int k0 = threadIdx.x * 4;  // 0..1020
    bf16x4 o;
    if (c < 96) {
        const float* src;
        int stride;
        if (c < 16)      { src = Wgm + c;        stride = 16; }
        else if (c < 32) { src = Wf + (c - 16);  stride = 16; }
        else             { src = Wg1 + (c - 32); stride = 64; }
#pragma unroll
        for (int j = 0; j < 4; j++) o[j] = (__bf16)src[(size_t)(k0 + j) * stride];
    } else {
        o[0] = o[1] = o[2] = o[3] = (__bf16)0.f;
    }
    *(bf16x4*)(W96T + (size_t)c * 1024 + k0) = o;
}

// ---------------------------------------------------------------------------
// bf16 GEMM, m97 structure + single-buffer DMA prefetch (round-8 verified)
// + XCD-aware bijective block swizzle. (unchanged round 10)
// ---------------------------------------------------------------------------
__global__ __launch_bounds__(256) void gemm_bt(const __bf16* __restrict__ A,
                                               const __bf16* B0, const __bf16* B1,
                                               const __bf16* B2, const __bf16* B3,
                                               float* C0, float* C1, float* C2, float* C3,
                                               int M, int N, int K) {
    constexpr int BK = 32;
    __shared__ __align__(16) __bf16 As[128 * BK];
    __shared__ __align__(16) __bf16 Bs[128 * BK];
    const int nwg = (int)(gridDim.x * gridDim.y);
    const int flat = (int)(blockIdx.y * gridDim.x + blockIdx.x);
    const int swz = (flat & 7) * (nwg >> 3) + (flat >> 3);
    const int bxs = swz % (int)gridDim.x, bys = swz / (int)gridDim.x;
    const int mat = bxs >> 3;
    const __bf16* B = (mat == 0) ? B0 : ((mat == 1) ? B1 : ((mat == 2) ? B2 : B3));
    float* C = (mat == 0) ? C0 : ((mat == 1) ? C1 : ((mat == 2) ? C2 : C3));
    const int Nn = (mat == 3) ? 128 : N;
    const int tid = threadIdx.x;
    const int lane = tid & 63;
    const int wave = tid >> 6;
    const int wm = (wave >> 1) * 64, wn = (wave & 1) * 64;
    const int bm = bys * 128, bn = (bxs & 7) * 128;
    const int l15 = lane & 15, quad = lane >> 4;

    const int srow = lane >> 2, scol = (lane & 3) * 8;
    const __bf16* gA = A + (size_t)(bm + wave * 16 + srow) * K + scol;
    const __bf16* gB = B + (size_t)(bn + wave * 16 + srow) * K + scol;
    const size_t rstep = (size_t)64 * K;
    __bf16* lA0 = &As[(wave * 16) * BK];
    __bf16* lA1 = &As[(wave * 16 + 64) * BK];
    __bf16* lB0 = &Bs[(wave * 16) * BK];
    __bf16* lB1 = &Bs[(wave * 16 + 64) * BK];

    f32x4 acc[4][4];
#pragma unroll
    for (int i = 0; i < 4; i++)
#pragma unroll
        for (int j = 0; j < 4; j++) acc[i][j] = (f32x4){0.f, 0.f, 0.f, 0.f};

    // prologue: DMA tile 0
    gl2lds16(gA, lA0);
    gl2lds16(gA + rstep, lA1);
    gl2lds16(gB, lB0);
    gl2lds16(gB + rstep, lB1);

    for (int kb = 0; kb < K; kb += BK) {
        asm volatile("s_waitcnt vmcnt(0)" ::: "memory");
        __syncthreads();  // tile kb landed in LDS (all waves)

        bf16x8 af[4], bfr[4];
#pragma unroll
        for (int i = 0; i < 4; i++)
            af[i] = *(const bf16x8*)&As[(wm + i * 16 + l15) * BK + quad * 8];
#pragma unroll
        for (int j = 0; j < 4; j++)
            bfr[j] = *(const bf16x8*)&Bs[(wn + j * 16 + l15) * BK + quad * 8];
        __syncthreads();  // all waves' frag reads drained -> LDS reusable

        if (kb + BK < K) {  // issue next tile's DMA; overlaps MFMA below
            gl2lds16(gA + kb + BK, lA0);
            gl2lds16(gA + kb + BK + rstep, lA1);
            gl2lds16(gB + kb + BK, lB0);
            gl2lds16(gB + kb + BK + rstep, lB1);
        }
        __builtin_amdgcn_sched_barrier(0);  // pin DMA issue before MFMA cluster

#pragma unroll
        for (int i = 0; i < 4; i++)
#pragma unroll
            for (int j = 0; j < 4; j++)
                acc[i][j] = MFMA16(af[i], bfr[j], acc[i][j]);
    }

#pragma unroll
    for (int i = 0; i < 4; i++) {
#pragma unroll
        for (int r = 0; r < 4; r++) {
            const int row = bm + wm + i * 16 + quad * 4 + r;
            float* cp = C + (size_t)row * Nn + bn + wn + l15;
#pragma unroll
            for (int j = 0; j < 4; j++) cp[j * 16] = acc[i][j][r];
        }
    }
}

// ---------------------------------------------------------------------------
// Tiny per-head scalars + g1 bf16 conversion from c96. (unchanged)
// ---------------------------------------------------------------------------
__global__ __launch_bounds__(256) void scal_prep(const float* __restrict__ c96,
                                                 float* __restrict__ lfb,
                                                 float* __restrict__ csb,
                                                 __bf16* __restrict__ g1b) {
    const int tid = threadIdx.x;
    const int row = blockIdx.x * 16 + (tid >> 4);
    const int h = tid & 15;
    const float* cr = c96 + (size_t)row * 128;
    const float sig = sigmoidf_(cr[16 + h]);       // lambda
    const float gm = -sigmoidf_(cr[h]);            // gamma
    lfb[(size_t)row * HH + h] = sig;
    csb[(size_t)row * HH + h] = gm * sig * sig;
    const int c4 = h * 4;
    bf16x4 o;
    o[0] = (__bf16)cr[32 + c4 + 0]; o[1] = (__bf16)cr[32 + c4 + 1];
    o[2] = (__bf16)cr[32 + c4 + 2]; o[3] = (__bf16)cr[32 + c4 + 3];
    *(bf16x4*)(g1b + (size_t)row * 64 + c4) = o;
}

// ---------------------------------------------------------------------------
// Chunked delta-rule, phase 1 — raw q/k, silu + k-l2norm in-block. (unchanged
// round 8/9 — verified)
// ---------------------------------------------------------------------------
__global__ __launch_bounds__(64) void chunk_prep(const float* __restrict__ qb,
                                                 const float* __restrict__ kb,
                                                 const float* __restrict__ lfb,
                                                 const float* __restrict__ csb,
                                                 __bf16* __restrict__ ck_hat,
                                                 __bf16* __restrict__ ck_q,
                                                 __bf16* __restrict__ ck_kbT,
                                                 __bf16* __restrict__ ck_M,
                                                 __bf16* __restrict__ ck_G,
                                                 float* __restrict__ ck_lam) {
    __shared__ __align__(16) __bf16 khL[32][72];
    __shared__ __align__(16) __bf16 kbL[32][72];
    __shared__ __align__(16) __bf16 qtL[32][72];
    __shared__ float Afp[32][33];
    __shared__ float scl[3][32];
    const int bx = blockIdx.x;
    const int bh = bx >> 6, ci = bx & 63;
    const int b = bh >> 4, h = bh & 15;
    const int l = threadIdx.x;
    const int l15 = l & 15, quad = l >> 4, t32 = l & 31;
    const size_t cid = (size_t)bh * NC + ci;

    const size_t mb = ((size_t)(b * NN + ci * CT) + t32) * HH + h;
    float c_t = csb[mb];
    float p = lfb[mb];
#pragma unroll
    for (int d = 1; d <= 16; d <<= 1) {
        float o = __shfl_up(p, d);
        p *= (t32 >= d) ? o : 1.f;
    }
    float pm1 = __shfl_up(p, 1);
    if (t32 == 0) pm1 = 1.f;
    const float lamT = __shfl(p, 31);
    if (l < 32) {
        scl[0][t32] = c_t * pm1;  // khat scale
        scl[1][t32] = 1.f / p;    // kbar scale
        scl[2][t32] = p;          // qtil scale
    }
    if (l == 0) ck_lam[cid] = lamT;
    __syncthreads();

    const size_t rb0 = ((size_t)(b * NN + ci * CT)) * DD + h * HD;
    __bf16* khG = ck_hat + cid * 2048;
    __bf16* qtG = ck_q + cid * 2048;
    __bf16* kTG = ck_kbT + cid * 2048;
#pragma unroll
    for (int rep = 0; rep < 8; rep++) {
        const int row = rep * 4 + quad;
        const int c4 = l15 * 4;
        float4 kv = *(const float4*)(kb + rb0 + (size_t)row * DD + c4);
        float4 qv = *(const float4*)(qb + rb0 + (size_t)row * DD + c4);
        // silu
        kv.x *= sigmoidf_(kv.x); kv.y *= sigmoidf_(kv.y);
        kv.z *= sigmoidf_(kv.z); kv.w *= sigmoidf_(kv.w);
        qv.x *= sigmoidf_(qv.x); qv.y *= sigmoidf_(qv.y);
        qv.z *= sigmoidf_(qv.z); qv.w *= sigmoidf_(qv.w);
        // l2 norm of silu'd k over the row (16 lanes x 4 elems = 64 d)
        float ss = kv.x * kv.x + kv.y * kv.y + kv.z * kv.z + kv.w * kv.w;
        ss += __shfl_xor(ss, 1); ss += __shfl_xor(ss, 2);
        ss += __shfl_xor(ss, 4); ss += __shfl_xor(ss, 8);
        const float inv = 1.f / fmaxf(sqrtf(ss), 1e-12f);
        const float sh = scl[0][row] * inv, sbr = scl[1][row] * inv, sq = scl[2][row];
        bf16x4 khv, kbv, qtv;
        khv[0] = (__bf16)(kv.x * sh); khv[1] = (__bf16)(kv.y * sh);
        khv[2] = (__bf16)(kv.z * sh); khv[3] = (__bf16)(kv.w * sh);
        kbv[0] = (__bf16)(kv.x * sbr); kbv[1] = (__bf16)(kv.y * sbr);
        kbv[2] = (__bf16)(kv.z * sbr); kbv[3] = (__bf16)(kv.w * sbr);
        qtv[0] = (__bf16)(qv.x * sq); qtv[1] = (__bf16)(qv.y * sq);
        qtv[2] = (__bf16)(qv.z * sq); qtv[3] = (__bf16)(qv.w * sq);
        *(bf16x4*)&khL[row][c4] = khv;
        *(bf16x4*)&kbL[row][c4] = kbv;
        *(bf16x4*)&qtL[row][c4] = qtv;
        *(bf16x4*)(khG + row * 64 + c4) = khv;
        *(bf16x4*)(qtG + row * 64 + c4) = qtv;
#pragma unroll
        for (int j = 0; j < 4; j++) kTG[(c4 + j) * 32 + row] = kbv[j];
    }
    __syncthreads();

    __bf16* GG = ck_G + cid * 1024;
#pragma unroll
    for (int mi = 0; mi < 2; mi++)
#pragma unroll
        for (int ni = 0; ni < 2; ni++) {
            f32x4 aA = (f32x4){0.f, 0.f, 0.f, 0.f};
            f32x4 aG = (f32x4){0.f, 0.f, 0.f, 0.f};
#pragma unroll
            for (int k2 = 0; k2 < 2; k2++) {
                bf16x8 bfr = *(const bf16x8*)&kbL[ni * 16 + l15][k2 * 32 + quad * 8];
                bf16x8 afr = *(const bf16x8*)&khL[mi * 16 + l15][k2 * 32 + quad * 8];
                bf16x8 qfr = *(const bf16x8*)&qtL[mi * 16 + l15][k2 * 32 + quad * 8];
                aA = MFMA16(afr, bfr, aA);
                aG = MFMA16(qfr, bfr, aG);
            }
#pragma unroll
            for (int r = 0; r < 4; r++) {
                const int row = mi * 16 + quad * 4 + r, col = ni * 16 + l15;
                Afp[row][col] = (col < row) ? aA[r] : 0.f;
                GG[row * 32 + col] = (__bf16)((col <= row) ? aG[r] : 0.f);
            }
        }
    __syncthreads();

    __bf16* MG = ck_M + cid * 1024;
    if (l < 32) {
        float m[32];
#pragma unroll
        for (int t = 0; t < 32; t++) {
            float r = (l == t) ? 1.f : 0.f;
#pragma unroll
            for (int s = 0; s < t; s++) r += Afp[t][s] * m[s];
            m[t] = r;
            MG[t * 32 + l] = (__bf16)r;
        }
    }
}

// ---------------------------------------------------------------------------
// Chunked delta-rule, phase 2 — ROUND-9 structure (4 v-slices, 128 blocks;
// verified 60.5 us) + __launch_bounds__(64, 1): lifts the VGPR cap (was 116,
// below the ~160 needed for two live FragSets + S) so the prefetched FragSet
// stays fully hoisted a compute-phase ahead of use. v raw; silu in compute.
// ---------------------------------------------------------------------------
struct FragSet {
    bf16x8 ka[2][2], qa[2][2], ma[2], ga[2], kba[4];
    f32x4 vv[2];
    float lam;
};

__global__ __launch_bounds__(64, 1) void chunk_scan(const __bf16* __restrict__ ck_hat,
                                                    const __bf16* __restrict__ ck_q,
                                                    const __bf16* __restrict__ ck_kbT,
                                                    const __bf16* __restrict__ ck_M,
                                                    const __bf16* __restrict__ ck_G,
                                                    const float* __restrict__ ck_lam,
                                                    const float* __restrict__ vb,
                                                    __bf16* __restrict__ obh) {
    __shared__ __align__(16) __bf16 Sbt[16][72];
    __shared__ __align__(16) __bf16 Vbt[16][40];
    __shared__ __align__(16) __bf16 Ubt[16][40];
    const int bx = blockIdx.x;
    const int bh = bx >> 2, vs = bx & 3;
    const int b = bh >> 4, h = bh & 15;
    const int l = threadIdx.x, l15 = l & 15, quad = l >> 4;
    const size_t cid0 = (size_t)bh * NC;
    const size_t vcol = (size_t)h * HD + vs * 16 + l15;
    const size_t rowb = (size_t)b * NN;

    f32x4 S[4];
#pragma unroll
    for (int dt = 0; dt < 4; dt++) S[dt] = (f32x4){0.f, 0.f, 0.f, 0.f};

    auto load = [&](FragSet& f, int ci) {
        const __bf16* khp = ck_hat + (cid0 + ci) * 2048;
        const __bf16* qp = ck_q + (cid0 + ci) * 2048;
        const __bf16* kTp = ck_kbT + (cid0 + ci) * 2048;
        const __bf16* Mp = ck_M + (cid0 + ci) * 1024;
        const __bf16* Gp = ck_G + (cid0 + ci) * 1024;
#pragma unroll
        for (int mi = 0; mi < 2; mi++) {
#pragma unroll
            for (int k2 = 0; k2 < 2; k2++) {
                f.ka[mi][k2] = *(const bf16x8*)(khp + (mi * 16 + l15) * 64 + k2 * 32 + quad * 8);
                f.qa[mi][k2] = *(const bf16x8*)(qp + (mi * 16 + l15) * 64 + k2 * 32 + quad * 8);
            }
            f.ma[mi] = *(const bf16x8*)(Mp + (mi * 16 + l15) * 32 + quad * 8);
            f.ga[mi] = *(const bf16x8*)(Gp + (mi * 16 + l15) * 32 + quad * 8);
        }
#pragma unroll
        for (int dt = 0; dt < 4; dt++)
            f.kba[dt] = *(const bf16x8*)(kTp + (dt * 16 + l15) * 32 + quad * 8);
        // RAW v — no dependent VALU here (keeps waitcnt deferred to use)
#pragma unroll
        for (int mi = 0; mi < 2; mi++)
#pragma unroll
            for (int r = 0; r < 4; r++)
                f.vv[mi][r] = vb[(rowb + ci * CT + mi * 16 + quad * 4 + r) * DD + vcol];
        f.lam = ck_lam[cid0 + ci];
    };

    auto compute = [&](const FragSet& f, int ci) {
        const f32x4 z = (f32x4){0.f, 0.f, 0.f, 0.f};
#pragma unroll
        for (int dt = 0; dt < 4; dt++) {
            bf16x4 t;
#pragma unroll
            for (int r = 0; r < 4; r++) t[r] = (__bf16)S[dt][r];
            *(bf16x4*)&Sbt[l15][dt * 16 + quad * 4] = t;
        }
        bf16x8 sb0 = *(const bf16x8*)&Sbt[l15][quad * 8];
        bf16x8 sb1 = *(const bf16x8*)&Sbt[l15][32 + quad * 8];
        f32x4 p0 = MFMA16(f.ka[0][0], sb0, z); p0 = MFMA16(f.ka[0][1], sb1, p0);
        f32x4 p1 = MFMA16(f.ka[1][0], sb0, z); p1 = MFMA16(f.ka[1][1], sb1, p1);
        // silu(v) here: VALU overlaps the MFMAs above, waitcnt lands here
#pragma unroll
        for (int r = 0; r < 4; r++) {
            const float v0 = f.vv[0][r], v1 = f.vv[1][r];
            p0[r] += v0 * sigmoidf_(v0);
            p1[r] += v1 * sigmoidf_(v1);
        }
        bf16x4 t0, t1;
#pragma unroll
        for (int r = 0; r < 4; r++) { t0[r] = (__bf16)p0[r]; t1[r] = (__bf16)p1[r]; }
        *(bf16x4*)&Vbt[l15][quad * 4] = t0;
        *(bf16x4*)&Vbt[l15][16 + quad * 4] = t1;
        bf16x8 vfr = *(const bf16x8*)&Vbt[l15][quad * 8];
        f32x4 u0 = MFMA16(f.ma[0], vfr, z);
        f32x4 u1 = MFMA16(f.ma[1], vfr, z);
#pragma unroll
        for (int r = 0; r < 4; r++) { t0[r] = (__bf16)u0[r]; t1[r] = (__bf16)u1[r]; }
        *(bf16x4*)&Ubt[l15][quad * 4] = t0;
        *(bf16x4*)&Ubt[l15][16 + quad * 4] = t1;
        bf16x8 ufr = *(const bf16x8*)&Ubt[l15][quad * 8];
        f32x4 o0 = MFMA16(f.qa[0][0], sb0, z); o0 = MFMA16(f.qa[0][1], sb1, o0);
        o0 = MFMA16(f.ga[0], ufr, o0);
        f32x4 o1 = MFMA16(f.qa[1][0], sb0, z); o1 = MFMA16(f.qa[1][1], sb1, o1);
        o1 = MFMA16(f.ga[1], ufr, o1);
#pragma unroll
        for (int r = 0; r < 4; r++) {
            obh[(rowb + ci * CT + quad * 4 + r) * DD + vcol] = (__bf16)o0[r];
            obh[(rowb + ci * CT + 16 + quad * 4 + r) * DD + vcol] = (__bf16)o1[r];
        }
#pragma unroll
        for (int dt = 0; dt < 4; dt++) {
            S[dt] = MFMA16(f.kba[dt], ufr, S[dt]);
#pragma unroll
            for (int r = 0; r < 4; r++) S[dt][r] *= f.lam;
        }
    };

    FragSet fA, fB;
    load(fA, 0);
    for (int ci = 0; ci < NC; ci += 2) {
        load(fB, ci + 1);
        __builtin_amdgcn_sched_barrier(0);
        compute(fA, ci);
        load(fA, (ci + 2 < NC) ? ci + 2 : NC - 1);
        __builtin_amdgcn_sched_barrier(0);
        compute(fB, ci + 1);
    }
}

// ---------------------------------------------------------------------------
// lnob = bf16( LayerNorm(o * sigmoid(gatep)) * norm_w ). (unchanged)
// ---------------------------------------------------------------------------
__global__ __launch_bounds__(256) void gate_ln_kernel(const __bf16* __restrict__ obh,
                                                      const float* __restrict__ gatep,
                                                      const float* __restrict__ nw,
                                                      __bf16* __restrict__ lnob) {
    const int r = blockIdx.x, tid = threadIdx.x;
    const int wav = tid >> 6, lane = tid & 63;
    __shared__ float red[8];
    const size_t rb = (size_t)r * DD;

    float vals[4];
    float s = 0.f;
#pragma unroll
    for (int p = 0; p < 4; p++) {
        const int j = tid + 256 * p;
        float xg = (float)obh[rb + j] * sigmoidf_(gatep[rb + j]);
        vals[p] = xg;
        s += xg;
    }
#pragma unroll
    for (int m = 1; m <= 32; m <<= 1) s += __shfl_xor(s, m);
    if (lane == 0) red[wav] = s;
    __syncthreads();
    const float mu = (red[0] + red[1] + red[2] + red[3]) * (1.f / 1024.f);

    float s2 = 0.f;
#pragma unroll
    for (int p = 0; p < 4; p++) { float d = vals[p] - mu; s2 += d * d; }
#pragma unroll
    for (int m = 1; m <= 32; m <<= 1) s2 += __shfl_xor(s2, m);
    if (lane == 0) red[4 + wav] = s2;
    __syncthreads();
    const float var = (red[4] + red[5] + red[6] + red[7]) * (1.f / 1024.f);
    const float rs = rsqrtf(var + 1e-5f);

#pragma unroll
    for (int p = 0; p < 4; p++) {
        const int j = tid + 256 * p;
        lnob[rb + j] = (__bf16)((vals[p] - mu) * rs * nw[j]);
    }
}

// ---------------------------------------------------------------------------
extern "C" void kernel_launch(void* const* d_in, const int* in_sizes, int n_in,
                              void* d_out, int out_size, void* d_ws, size_t ws_size,
                              hipStream_t stream) {
    const float* x   = (const float*)d_in[0];
    const float* Wq  = (const float*)d_in[1];
    const float* Wk  = (const float*)d_in[2];
    const float* Wv  = (const float*)d_in[3];
    const float* Wgm = (const float*)d_in[4];  // Wgamma
    const float* Wf  = (const float*)d_in[5];
    const float* Wg1 = (const float*)d_in[6];
    const float* Wg2 = (const float*)d_in[7];
    const float* Wo  = (const float*)d_in[8];
    const float* nw  = (const float*)d_in[9];
    float* out = (float*)d_out;

    float* w = (float*)d_ws;
    float* qb    = w;                     // 4096x1024 f32 raw q (later lnob bf16)
    float* kb    = qb + 4194304;          // raw k
    float* vb    = kb + 4194304;          // raw v
    float* gatep = vb + 4194304;
    __bf16* g1b  = (__bf16*)(gatep + 4194304);  // 4096x64 bf16
    float* lfb   = gatep + 4194304 + 131072;    // 4096x16 (lambda)
    float* csb   = lfb + 65536;                 // 4096x16 (gamma*lambda^2)
    __bf16* obh  = (__bf16*)(csb + 65536);      // 4096x1024 bf16 scan output
    float* cw    = csb + 65536 + 2097152;       // chunk workspace
    __bf16* ck_hat = (__bf16*)cw;               // [2048][32][64] bf16
    __bf16* ck_q   = (__bf16*)(cw + 2097152);   // [2048][32][64]
    __bf16* ck_kbT = (__bf16*)(cw + 4194304);   // [2048][64][32]
    __bf16* ck_M   = (__bf16*)(cw + 6291456);   // [2048][32][32]
    __bf16* ck_G   = (__bf16*)(cw + 7340032);   // [2048][32][32]
    float*  ck_lam = cw + 8388608;              // [2048]
    float* nw2   = cw + 8390656;
    __bf16* xb   = (__bf16*)nw2;                // 4096x1024 bf16
    __bf16* WqT  = (__bf16*)(nw2 + 2097152);    // 1024x1024 bf16 (transposed)
    __bf16* WkT  = (__bf16*)(nw2 + 2621440);
    __bf16* WvT  = (__bf16*)(nw2 + 3145728);
    __bf16* WoT  = (__bf16*)(nw2 + 3670016);
    __bf16* Wg2T = (__bf16*)(nw2 + 4194304);    // 1024x64 bf16
    __bf16* W96T = (__bf16*)(nw2 + 4227072);    // 128x1024 bf16 (padded)
    float* c96   = nw2 + 4292608;               // 4096x128 f32
    __bf16* lnob = (__bf16*)qb;                 // reuse qb

    dim3 blk(256);
    xcvt<<<2048, blk, 0, stream>>>(x, xb);
    wtrans<<<dim3(16, 16, 4), blk, 0, stream>>>(Wq, Wk, Wv, Wo, WqT, WkT, WvT, WoT,
                                                DD, DD);
    wtrans<<<dim3(16, 1, 1), blk, 0, stream>>>(Wg2, Wg2, Wg2, Wg2, Wg2T, Wg2T, Wg2T,
                                               Wg2T, HD, DD);
    wtrans96<<<128, blk, 0, stream>>>(Wgm, Wf, Wg1, W96T);
    // fused q,k,v + 96-col proj: 25 x-blocks = 3x8 col-tiles + 1 (mat 3, N=128)
    gemm_bt<<<dim3(25, 32), blk, 0, stream>>>(xb, WqT, WkT, WvT, W96T,
                                              qb, kb, vb, c96, RR, DD, DD);
    scal_prep<<<RR / 16, blk, 0, stream>>>(c96, lfb, csb, g1b);
    gemm_bt<<<dim3(8, 32), blk, 0, stream>>>(g1b, Wg2T, Wg2T, Wg2T, Wg2T,
                                             gatep, gatep, gatep, gatep, RR, DD, HD);
    chunk_prep<<<32 * NC, 64, 0, stream>>>(qb, kb, lfb, csb,
                                           ck_hat, ck_q, ck_kbT, ck_M, ck_G, ck_lam);
    chunk_scan<<<128, 64, 0, stream>>>(ck_hat, ck_q, ck_kbT, ck_M, ck_G, ck_lam, vb, obh);
    gate_ln_kernel<<<RR, blk, 0, stream>>>(obh, gatep, nw, lnob);
    gemm_bt<<<dim3(8, 32), blk, 0, stream>>>(lnob, WoT, WoT, WoT, WoT,
                                             out, out, out, out, RR, DD, DD);
}

// Round 12
// 241.763 us; speedup vs baseline: 1.2176x; 1.0661x over previous
//
#include <hip/hip_runtime.h>

#define BB 2
#define NN 2048
#define DD 1024
#define HH 16
#define HD 64
#define RR (BB * NN)  // 4096 rows
#define CT 32         // chunk length (steps)
#define NC (NN / CT)  // 64 chunks per (b,h)

typedef __bf16 bf16x8 __attribute__((ext_vector_type(8)));
typedef __bf16 bf16x4 __attribute__((ext_vector_type(4)));
typedef float f32x4 __attribute__((ext_vector_type(4)));
typedef float f32x2 __attribute__((ext_vector_type(2)));

__device__ __forceinline__ float sigmoidf_(float x) { return 1.f / (1.f + __expf(-x)); }

#define MFMA16(a, b, c) __builtin_amdgcn_mfma_f32_16x16x32_bf16((a), (b), (c), 0, 0, 0)

// async global -> LDS DMA (gfx950). LDS dst is wave-uniform; lane i's data
// lands at dst + i*size. Global src is a normal per-lane address.
__device__ __forceinline__ void gl2lds16(const void* g, void* l) {
    __builtin_amdgcn_global_load_lds((const __attribute__((address_space(1))) void*)g,
                                     (__attribute__((address_space(3))) void*)l, 16, 0, 0);
}

// ---------------------------------------------------------------------------
// x (f32) -> bf16, 8 elems/thread.
// ---------------------------------------------------------------------------
__global__ __launch_bounds__(256) void xcvt(const float* __restrict__ x,
                                            __bf16* __restrict__ xb) {
    const size_t i = ((size_t)blockIdx.x * 256 + threadIdx.x) * 8;
    float4 a = *(const float4*)(x + i);
    float4 b = *(const float4*)(x + i + 4);
    bf16x8 o;
    o[0] = (__bf16)a.x; o[1] = (__bf16)a.y; o[2] = (__bf16)a.z; o[3] = (__bf16)a.w;
    o[4] = (__bf16)b.x; o[5] = (__bf16)b.y; o[6] = (__bf16)b.z; o[7] = (__bf16)b.w;
    *(bf16x8*)(xb + i) = o;
}

// ---------------------------------------------------------------------------
// Weight transpose+convert: S (f32, [K][N]) -> D (bf16, [N][K]). (unchanged)
// ---------------------------------------------------------------------------
__global__ __launch_bounds__(256) void wtrans(const float* S0, const float* S1,
                                              const float* S2, const float* S3,
                                              __bf16* D0, __bf16* D1,
                                              __bf16* D2, __bf16* D3,
                                              int K, int N) {
    __shared__ float t[64][65];
    const int z = blockIdx.z;
    const float* S = (z == 0) ? S0 : ((z == 1) ? S1 : ((z == 2) ? S2 : S3));
    __bf16* D = (z == 0) ? D0 : ((z == 1) ? D1 : ((z == 2) ? D2 : D3));
    const int tid = threadIdx.x;
    const int ti = blockIdx.y * 64;  // k tile
    const int tj = blockIdx.x * 64;  // n tile
    const int r = tid >> 2, c0 = (tid & 3) * 16;
    const float* sp = S + (size_t)(ti + r) * N + tj + c0;
#pragma unroll
    for (int p = 0; p < 4; p++) {
        float4 v = *(const float4*)(sp + 4 * p);
        t[r][c0 + 4 * p + 0] = v.x; t[r][c0 + 4 * p + 1] = v.y;
        t[r][c0 + 4 * p + 2] = v.z; t[r][c0 + 4 * p + 3] = v.w;
    }
    __syncthreads();
    bf16x8 o0, o1;
#pragma unroll
    for (int j = 0; j < 8; j++) o0[j] = (__bf16)t[c0 + j][r];
#pragma unroll
    for (int j = 0; j < 8; j++) o1[j] = (__bf16)t[c0 + 8 + j][r];
    __bf16* dp = D + (size_t)(tj + r) * K + ti + c0;
    *(bf16x8*)dp = o0;
    *(bf16x8*)(dp + 8) = o1;
}

// ---------------------------------------------------------------------------
// W96T[c][k] (bf16, 128x1024, zero-padded rows 96..127) = [Wgamma|Wf|Wg1]^T.
// ---------------------------------------------------------------------------
__global__ __launch_bounds__(256) void wtrans96(const float* __restrict__ Wgm,
                                                const float* __restrict__ Wf,
                                                const float* __restrict__ Wg1,
                                                __bf16* __restrict__ W96T) {
    const int c = blockIdx.x;        // 0..127
    const int k0 = threadIdx.x * 4;  // 0..1020
    bf16x4 o;
    if (c < 96) {
        const float* src;
        int stride;
        if (c < 16)      { src = Wgm + c;        stride = 16; }
        else if (c < 32) { src = Wf + (c - 16);  stride = 16; }
        else             { src = Wg1 + (c - 32); stride = 64; }
#pragma unroll
        for (int j = 0; j < 4; j++) o[j] = (__bf16)src[(size_t)(k0 + j) * stride];
    } else {
        o[0] = o[1] = o[2] = o[3] = (__bf16)0.f;
    }
    *(bf16x4*)(W96T + (size_t)c * 1024 + k0) = o;
}

// ---------------------------------------------------------------------------
// bf16 GEMM, m97 structure + single-buffer DMA prefetch + XCD swizzle.
// (unchanged rounds 8-10 — verified)
// ---------------------------------------------------------------------------
__global__ __launch_bounds__(256) void gemm_bt(const __bf16* __restrict__ A,
                                               const __bf16* B0, const __bf16* B1,
                                               const __bf16* B2, const __bf16* B3,
                                               float* C0, float* C1, float* C2, float* C3,
                                               int M, int N, int K) {
    constexpr int BK = 32;
    __shared__ __align__(16) __bf16 As[128 * BK];
    __shared__ __align__(16) __bf16 Bs[128 * BK];
    const int nwg = (int)(gridDim.x * gridDim.y);
    const int flat = (int)(blockIdx.y * gridDim.x + blockIdx.x);
    const int swz = (flat & 7) * (nwg >> 3) + (flat >> 3);
    const int bxs = swz % (int)gridDim.x, bys = swz / (int)gridDim.x;
    const int mat = bxs >> 3;
    const __bf16* B = (mat == 0) ? B0 : ((mat == 1) ? B1 : ((mat == 2) ? B2 : B3));
    float* C = (mat == 0) ? C0 : ((mat == 1) ? C1 : ((mat == 2) ? C2 : C3));
    const int Nn = (mat == 3) ? 128 : N;
    const int tid = threadIdx.x;
    const int lane = tid & 63;
    const int wave = tid >> 6;
    const int wm = (wave >> 1) * 64, wn = (wave & 1) * 64;
    const int bm = bys * 128, bn = (bxs & 7) * 128;
    const int l15 = lane & 15, quad = lane >> 4;

    const int srow = lane >> 2, scol = (lane & 3) * 8;
    const __bf16* gA = A + (size_t)(bm + wave * 16 + srow) * K + scol;
    const __bf16* gB = B + (size_t)(bn + wave * 16 + srow) * K + scol;
    const size_t rstep = (size_t)64 * K;
    __bf16* lA0 = &As[(wave * 16) * BK];
    __bf16* lA1 = &As[(wave * 16 + 64) * BK];
    __bf16* lB0 = &Bs[(wave * 16) * BK];
    __bf16* lB1 = &Bs[(wave * 16 + 64) * BK];

    f32x4 acc[4][4];
#pragma unroll
    for (int i = 0; i < 4; i++)
#pragma unroll
        for (int j = 0; j < 4; j++) acc[i][j] = (f32x4){0.f, 0.f, 0.f, 0.f};

    // prologue: DMA tile 0
    gl2lds16(gA, lA0);
    gl2lds16(gA + rstep, lA1);
    gl2lds16(gB, lB0);
    gl2lds16(gB + rstep, lB1);

    for (int kb = 0; kb < K; kb += BK) {
        asm volatile("s_waitcnt vmcnt(0)" ::: "memory");
        __syncthreads();  // tile kb landed in LDS (all waves)

        bf16x8 af[4], bfr[4];
#pragma unroll
        for (int i = 0; i < 4; i++)
            af[i] = *(const bf16x8*)&As[(wm + i * 16 + l15) * BK + quad * 8];
#pragma unroll
        for (int j = 0; j < 4; j++)
            bfr[j] = *(const bf16x8*)&Bs[(wn + j * 16 + l15) * BK + quad * 8];
        __syncthreads();  // all waves' frag reads drained -> LDS reusable

        if (kb + BK < K) {  // issue next tile's DMA; overlaps MFMA below
            gl2lds16(gA + kb + BK, lA0);
            gl2lds16(gA + kb + BK + rstep, lA1);
            gl2lds16(gB + kb + BK, lB0);
            gl2lds16(gB + kb + BK + rstep, lB1);
        }
        __builtin_amdgcn_sched_barrier(0);  // pin DMA issue before MFMA cluster

#pragma unroll
        for (int i = 0; i < 4; i++)
#pragma unroll
            for (int j = 0; j < 4; j++)
                acc[i][j] = MFMA16(af[i], bfr[j], acc[i][j]);
    }

#pragma unroll
    for (int i = 0; i < 4; i++) {
#pragma unroll
        for (int r = 0; r < 4; r++) {
            const int row = bm + wm + i * 16 + quad * 4 + r;
            float* cp = C + (size_t)row * Nn + bn + wn + l15;
#pragma unroll
            for (int j = 0; j < 4; j++) cp[j * 16] = acc[i][j][r];
        }
    }
}

// ---------------------------------------------------------------------------
// Tiny per-head scalars + g1 bf16 conversion from c96. (unchanged)
// ---------------------------------------------------------------------------
__global__ __launch_bounds__(256) void scal_prep(const float* __restrict__ c96,
                                                 float* __restrict__ lfb,
                                                 float* __restrict__ csb,
                                                 __bf16* __restrict__ g1b) {
    const int tid = threadIdx.x;
    const int row = blockIdx.x * 16 + (tid >> 4);
    const int h = tid & 15;
    const float* cr = c96 + (size_t)row * 128;
    const float sig = sigmoidf_(cr[16 + h]);       // lambda
    const float gm = -sigmoidf_(cr[h]);            // gamma
    lfb[(size_t)row * HH + h] = sig;
    csb[(size_t)row * HH + h] = gm * sig * sig;
    const int c4 = h * 4;
    bf16x4 o;
    o[0] = (__bf16)cr[32 + c4 + 0]; o[1] = (__bf16)cr[32 + c4 + 1];
    o[2] = (__bf16)cr[32 + c4 + 2]; o[3] = (__bf16)cr[32 + c4 + 3];
    *(bf16x4*)(g1b + (size_t)row * 64 + c4) = o;
}

// ---------------------------------------------------------------------------
// Chunked delta-rule, phase 1 — raw q/k/v, silu + k-l2norm in-block, PLUS
// the S-independent hoist: MKhat = M@Khat and U_v = M@silu(V), both 32x64,
// computed per chunk with MFMA (M, Khat^T, Vs^T staged in LDS). These remove
// one LDS round-trip + one MFMA stage + all v traffic from the serial scan.
// Outputs: ck_q (Qtil), ck_kbT, ck_G, ck_mkh (MKhat), ck_uvT (U_v^T), lamT.
// ---------------------------------------------------------------------------
__global__ __launch_bounds__(64) void chunk_prep(const float* __restrict__ qb,
                                                 const float* __restrict__ kb,
                                                 const float* __restrict__ vb,
                                                 const float* __restrict__ lfb,
                                                 const float* __restrict__ csb,
                                                 __bf16* __restrict__ ck_mkh,
                                                 __bf16* __restrict__ ck_q,
                                                 __bf16* __restrict__ ck_kbT,
                                                 __bf16* __restrict__ ck_G,
                                                 __bf16* __restrict__ ck_uvT,
                                                 float* __restrict__ ck_lam) {
    __shared__ __align__(16) __bf16 khL[32][72];
    __shared__ __align__(16) __bf16 kbL[32][72];
    __shared__ __align__(16) __bf16 qtL[32][72];
    __shared__ __align__(16) __bf16 khT[64][40];  // Khat^T [d][t]
    __shared__ __align__(16) __bf16 vsT[64][40];  // silu(V)^T [d][t]
    __shared__ __align__(16) __bf16 Ms[32][40];   // M row-major [t_out][t_in]
    __shared__ float Afp[32][33];
    __shared__ float scl[3][32];
    const int bx = blockIdx.x;
    const int bh = bx >> 6, ci = bx & 63;
    const int b = bh >> 4, h = bh & 15;
    const int l = threadIdx.x;
    const int l15 = l & 15, quad = l >> 4, t32 = l & 31;
    const size_t cid = (size_t)bh * NC + ci;

    const size_t mb = ((size_t)(b * NN + ci * CT) + t32) * HH + h;
    float c_t = csb[mb];
    float p = lfb[mb];
#pragma unroll
    for (int d = 1; d <= 16; d <<= 1) {
        float o = __shfl_up(p, d);
        p *= (t32 >= d) ? o : 1.f;
    }
    float pm1 = __shfl_up(p, 1);
    if (t32 == 0) pm1 = 1.f;
    const float lamT = __shfl(p, 31);
    if (l < 32) {
        scl[0][t32] = c_t * pm1;  // khat scale
        scl[1][t32] = 1.f / p;    // kbar scale
        scl[2][t32] = p;          // qtil scale
    }
    if (l == 0) ck_lam[cid] = lamT;
    __syncthreads();

    const size_t rb0 = ((size_t)(b * NN + ci * CT)) * DD + h * HD;
    __bf16* qtG = ck_q + cid * 2048;
    __bf16* kTG = ck_kbT + cid * 2048;
#pragma unroll
    for (int rep = 0; rep < 8; rep++) {
        const int row = rep * 4 + quad;
        const int c4 = l15 * 4;
        float4 kv = *(const float4*)(kb + rb0 + (size_t)row * DD + c4);
        float4 qv = *(const float4*)(qb + rb0 + (size_t)row * DD + c4);
        float4 vv = *(const float4*)(vb + rb0 + (size_t)row * DD + c4);
        // silu
        kv.x *= sigmoidf_(kv.x); kv.y *= sigmoidf_(kv.y);
        kv.z *= sigmoidf_(kv.z); kv.w *= sigmoidf_(kv.w);
        qv.x *= sigmoidf_(qv.x); qv.y *= sigmoidf_(qv.y);
        qv.z *= sigmoidf_(qv.z); qv.w *= sigmoidf_(qv.w);
        vv.x *= sigmoidf_(vv.x); vv.y *= sigmoidf_(vv.y);
        vv.z *= sigmoidf_(vv.z); vv.w *= sigmoidf_(vv.w);
        // l2 norm of silu'd k over the row (16 lanes x 4 elems = 64 d)
        float ss = kv.x * kv.x + kv.y * kv.y + kv.z * kv.z + kv.w * kv.w;
        ss += __shfl_xor(ss, 1); ss += __shfl_xor(ss, 2);
        ss += __shfl_xor(ss, 4); ss += __shfl_xor(ss, 8);
        const float inv = 1.f / fmaxf(sqrtf(ss), 1e-12f);
        const float sh = scl[0][row] * inv, sbr = scl[1][row] * inv, sq = scl[2][row];
        bf16x4 khv, kbv, qtv;
        khv[0] = (__bf16)(kv.x * sh); khv[1] = (__bf16)(kv.y * sh);
        khv[2] = (__bf16)(kv.z * sh); khv[3] = (__bf16)(kv.w * sh);
        kbv[0] = (__bf16)(kv.x * sbr); kbv[1] = (__bf16)(kv.y * sbr);
        kbv[2] = (__bf16)(kv.z * sbr); kbv[3] = (__bf16)(kv.w * sbr);
        qtv[0] = (__bf16)(qv.x * sq); qtv[1] = (__bf16)(qv.y * sq);
        qtv[2] = (__bf16)(qv.z * sq); qtv[3] = (__bf16)(qv.w * sq);
        *(bf16x4*)&khL[row][c4] = khv;
        *(bf16x4*)&kbL[row][c4] = kbv;
        *(bf16x4*)&qtL[row][c4] = qtv;
        *(bf16x4*)(qtG + row * 64 + c4) = qtv;
#pragma unroll
        for (int j = 0; j < 4; j++) {
            kTG[(c4 + j) * 32 + row] = kbv[j];
            khT[c4 + j][row] = khv[j];
        }
        vsT[c4 + 0][row] = (__bf16)vv.x; vsT[c4 + 1][row] = (__bf16)vv.y;
        vsT[c4 + 2][row] = (__bf16)vv.z; vsT[c4 + 3][row] = (__bf16)vv.w;
    }
    __syncthreads();

    __bf16* GG = ck_G + cid * 1024;
#pragma unroll
    for (int mi = 0; mi < 2; mi++)
#pragma unroll
        for (int ni = 0; ni < 2; ni++) {
            f32x4 aA = (f32x4){0.f, 0.f, 0.f, 0.f};
            f32x4 aG = (f32x4){0.f, 0.f, 0.f, 0.f};
#pragma unroll
            for (int k2 = 0; k2 < 2; k2++) {
                bf16x8 bfr = *(const bf16x8*)&kbL[ni * 16 + l15][k2 * 32 + quad * 8];
                bf16x8 afr = *(const bf16x8*)&khL[mi * 16 + l15][k2 * 32 + quad * 8];
                bf16x8 qfr = *(const bf16x8*)&qtL[mi * 16 + l15][k2 * 32 + quad * 8];
                aA = MFMA16(afr, bfr, aA);
                aG = MFMA16(qfr, bfr, aG);
            }
#pragma unroll
            for (int r = 0; r < 4; r++) {
                const int row = mi * 16 + quad * 4 + r, col = ni * 16 + l15;
                Afp[row][col] = (col < row) ? aA[r] : 0.f;
                GG[row * 32 + col] = (__bf16)((col <= row) ? aG[r] : 0.f);
            }
        }
    __syncthreads();

    // M = (I-A)^-1 via fp32 forward substitution; lane = column. -> Ms LDS
    if (l < 32) {
        float m[32];
#pragma unroll
        for (int t = 0; t < 32; t++) {
            float r = (l == t) ? 1.f : 0.f;
#pragma unroll
            for (int s = 0; s < t; s++) r += Afp[t][s] * m[s];
            m[t] = r;
            Ms[t][l] = (__bf16)r;
        }
    }
    __syncthreads();

    // MKhat = M @ Khat (A=Ms rows, B^T=khT rows); U_v = M @ silu(V).
    const f32x4 z = (f32x4){0.f, 0.f, 0.f, 0.f};
    __bf16* mkhG = ck_mkh + cid * 2048;
    __bf16* uvTG = ck_uvT + cid * 2048;
#pragma unroll
    for (int mi = 0; mi < 2; mi++) {
        bf16x8 am = *(const bf16x8*)&Ms[mi * 16 + l15][quad * 8];
#pragma unroll
        for (int ni = 0; ni < 4; ni++) {
            bf16x8 bk = *(const bf16x8*)&khT[ni * 16 + l15][quad * 8];
            bf16x8 bv = *(const bf16x8*)&vsT[ni * 16 + l15][quad * 8];
            f32x4 aM = MFMA16(am, bk, z);
            f32x4 aV = MFMA16(am, bv, z);
#pragma unroll
            for (int r = 0; r < 4; r++) {
                const int trow = mi * 16 + quad * 4 + r, col = ni * 16 + l15;
                mkhG[trow * 64 + col] = (__bf16)aM[r];
                uvTG[col * 32 + trow] = (__bf16)aV[r];  // transposed [d][t]
            }
        }
    }
}

// ---------------------------------------------------------------------------
// Chunked delta-rule, phase 2 — shortened chain:
//   U = MKhat@S0 + U_v   (one LDS RT for S0-frags, one MFMA stage)
//   U -> Ubt -> ufr      (second LDS RT)
//   O = Qtil@S0 + G@U ; S = lam*(S0 + KbarT@U)
// U_v loaded as raw bf16x4 (no dependent VALU in load — round-8 lesson);
// converted in compute. 128 blocks (bh x 4 v-slices), round-9 verified shape.
// ---------------------------------------------------------------------------
struct FragSet {
    bf16x8 mkha[2][2], qa[2][2], ga[2], kba[4];
    bf16x4 uvb[2];
    float lam;
};

__global__ __launch_bounds__(64) void chunk_scan(const __bf16* __restrict__ ck_mkh,
                                                 const __bf16* __restrict__ ck_q,
                                                 const __bf16* __restrict__ ck_kbT,
                                                 const __bf16* __restrict__ ck_G,
                                                 const __bf16* __restrict__ ck_uvT,
                                                 const float* __restrict__ ck_lam,
                                                 __bf16* __restrict__ obh) {
    __shared__ __align__(16) __bf16 Sbt[16][72];
    __shared__ __align__(16) __bf16 Ubt[16][40];
    const int bx = blockIdx.x;
    const int bh = bx >> 2, vs = bx & 3;
    const int b = bh >> 4, h = bh & 15;
    const int l = threadIdx.x, l15 = l & 15, quad = l >> 4;
    const size_t cid0 = (size_t)bh * NC;
    const size_t vcol = (size_t)h * HD + vs * 16 + l15;
    const size_t rowb = (size_t)b * NN;

    f32x4 S[4];
#pragma unroll
    for (int dt = 0; dt < 4; dt++) S[dt] = (f32x4){0.f, 0.f, 0.f, 0.f};

    auto load = [&](FragSet& f, int ci) {
        const __bf16* mkp = ck_mkh + (cid0 + ci) * 2048;
        const __bf16* qp = ck_q + (cid0 + ci) * 2048;
        const __bf16* kTp = ck_kbT + (cid0 + ci) * 2048;
        const __bf16* Gp = ck_G + (cid0 + ci) * 1024;
        const __bf16* uvp = ck_uvT + (cid0 + ci) * 2048;
#pragma unroll
        for (int mi = 0; mi < 2; mi++) {
#pragma unroll
            for (int k2 = 0; k2 < 2; k2++) {
                f.mkha[mi][k2] = *(const bf16x8*)(mkp + (mi * 16 + l15) * 64 + k2 * 32 + quad * 8);
                f.qa[mi][k2] = *(const bf16x8*)(qp + (mi * 16 + l15) * 64 + k2 * 32 + quad * 8);
            }
            f.ga[mi] = *(const bf16x8*)(Gp + (mi * 16 + l15) * 32 + quad * 8);
            // raw bf16x4 — no dependent VALU here (waitcnt stays deferred)
            f.uvb[mi] = *(const bf16x4*)(uvp + (vs * 16 + l15) * 32 + mi * 16 + quad * 4);
        }
#pragma unroll
        for (int dt = 0; dt < 4; dt++)
            f.kba[dt] = *(const bf16x8*)(kTp + (dt * 16 + l15) * 32 + quad * 8);
        f.lam = ck_lam[cid0 + ci];
    };

    auto compute = [&](const FragSet& f, int ci) {
        const f32x4 z = (f32x4){0.f, 0.f, 0.f, 0.f};
#pragma unroll
        for (int dt = 0; dt < 4; dt++) {
            bf16x4 t;
#pragma unroll
            for (int r = 0; r < 4; r++) t[r] = (__bf16)S[dt][r];
            *(bf16x4*)&Sbt[l15][dt * 16 + quad * 4] = t;
        }
        bf16x8 sb0 = *(const bf16x8*)&Sbt[l15][quad * 8];
        bf16x8 sb1 = *(const bf16x8*)&Sbt[l15][32 + quad * 8];
        // U = MKhat @ S0 + U_v
        f32x4 u0 = MFMA16(f.mkha[0][0], sb0, z); u0 = MFMA16(f.mkha[0][1], sb1, u0);
        f32x4 u1 = MFMA16(f.mkha[1][0], sb0, z); u1 = MFMA16(f.mkha[1][1], sb1, u1);
#pragma unroll
        for (int r = 0; r < 4; r++) {
            u0[r] += (float)f.uvb[0][r];
            u1[r] += (float)f.uvb[1][r];
        }
        bf16x4 t0, t1;
#pragma unroll
        for (int r = 0; r < 4; r++) { t0[r] = (__bf16)u0[r]; t1[r] = (__bf16)u1[r]; }
        *(bf16x4*)&Ubt[l15][quad * 4] = t0;
        *(bf16x4*)&Ubt[l15][16 + quad * 4] = t1;
        bf16x8 ufr = *(const bf16x8*)&Ubt[l15][quad * 8];
        // O = Qtil @ S0 + G @ U
        f32x4 o0 = MFMA16(f.qa[0][0], sb0, z); o0 = MFMA16(f.qa[0][1], sb1, o0);
        o0 = MFMA16(f.ga[0], ufr, o0);
        f32x4 o1 = MFMA16(f.qa[1][0], sb0, z); o1 = MFMA16(f.qa[1][1], sb1, o1);
        o1 = MFMA16(f.ga[1], ufr, o1);
#pragma unroll
        for (int r = 0; r < 4; r++) {
            obh[(rowb + ci * CT + quad * 4 + r) * DD + vcol] = (__bf16)o0[r];
            obh[(rowb + ci * CT + 16 + quad * 4 + r) * DD + vcol] = (__bf16)o1[r];
        }
        // S = LamT * (S0 + KbarT @ U)
#pragma unroll
        for (int dt = 0; dt < 4; dt++) {
            S[dt] = MFMA16(f.kba[dt], ufr, S[dt]);
#pragma unroll
            for (int r = 0; r < 4; r++) S[dt][r] *= f.lam;
        }
    };

    FragSet fA, fB;
    load(fA, 0);
    for (int ci = 0; ci < NC; ci += 2) {
        load(fB, ci + 1);
        __builtin_amdgcn_sched_barrier(0);
        compute(fA, ci);
        load(fA, (ci + 2 < NC) ? ci + 2 : NC - 1);
        __builtin_amdgcn_sched_barrier(0);
        compute(fB, ci + 1);
    }
}

// ---------------------------------------------------------------------------
// lnob = bf16( LayerNorm(o * sigmoid(gatep)) * norm_w ). (unchanged)
// ---------------------------------------------------------------------------
__global__ __launch_bounds__(256) void gate_ln_kernel(const __bf16* __restrict__ obh,
                                                      const float* __restrict__ gatep,
                                                      const float* __restrict__ nw,
                                                      __bf16* __restrict__ lnob) {
    const int r = blockIdx.x, tid = threadIdx.x;
    const int wav = tid >> 6, lane = tid & 63;
    __shared__ float red[8];
    const size_t rb = (size_t)r * DD;

    float vals[4];
    float s = 0.f;
#pragma unroll
    for (int p = 0; p < 4; p++) {
        const int j = tid + 256 * p;
        float xg = (float)obh[rb + j] * sigmoidf_(gatep[rb + j]);
        vals[p] = xg;
        s += xg;
    }
#pragma unroll
    for (int m = 1; m <= 32; m <<= 1) s += __shfl_xor(s, m);
    if (lane == 0) red[wav] = s;
    __syncthreads();
    const float mu = (red[0] + red[1] + red[2] + red[3]) * (1.f / 1024.f);

    float s2 = 0.f;
#pragma unroll
    for (int p = 0; p < 4; p++) { float d = vals[p] - mu; s2 += d * d; }
#pragma unroll
    for (int m = 1; m <= 32; m <<= 1) s2 += __shfl_xor(s2, m);
    if (lane == 0) red[4 + wav] = s2;
    __syncthreads();
    const float var = (red[4] + red[5] + red[6] + red[7]) * (1.f / 1024.f);
    const float rs = rsqrtf(var + 1e-5f);

#pragma unroll
    for (int p = 0; p < 4; p++) {
        const int j = tid + 256 * p;
        lnob[rb + j] = (__bf16)((vals[p] - mu) * rs * nw[j]);
    }
}

// ---------------------------------------------------------------------------
extern "C" void kernel_launch(void* const* d_in, const int* in_sizes, int n_in,
                              void* d_out, int out_size, void* d_ws, size_t ws_size,
                              hipStream_t stream) {
    const float* x   = (const float*)d_in[0];
    const float* Wq  = (const float*)d_in[1];
    const float* Wk  = (const float*)d_in[2];
    const float* Wv  = (const float*)d_in[3];
    const float* Wgm = (const float*)d_in[4];  // Wgamma
    const float* Wf  = (const float*)d_in[5];
    const float* Wg1 = (const float*)d_in[6];
    const float* Wg2 = (const float*)d_in[7];
    const float* Wo  = (const float*)d_in[8];
    const float* nw  = (const float*)d_in[9];
    float* out = (float*)d_out;

    float* w = (float*)d_ws;
    float* qb    = w;                     // 4096x1024 f32 raw q (later lnob bf16)
    float* kb    = qb + 4194304;          // raw k
    float* vb    = kb + 4194304;          // raw v
    float* gatep = vb + 4194304;
    __bf16* g1b  = (__bf16*)(gatep + 4194304);  // 4096x64 bf16
    float* lfb   = gatep + 4194304 + 131072;    // 4096x16 (lambda)
    float* csb   = lfb + 65536;                 // 4096x16 (gamma*lambda^2)
    __bf16* obh  = (__bf16*)(csb + 65536);      // 4096x1024 bf16 scan output
    float* cw    = csb + 65536 + 2097152;       // chunk workspace
    __bf16* ck_mkh = (__bf16*)cw;               // [2048][32][64] bf16 (MKhat)
    __bf16* ck_q   = (__bf16*)(cw + 2097152);   // [2048][32][64]
    __bf16* ck_kbT = (__bf16*)(cw + 4194304);   // [2048][64][32]
    __bf16* ck_G   = (__bf16*)(cw + 6291456);   // [2048][32][32]
    __bf16* ck_uvT = (__bf16*)(cw + 7340032);   // [2048][64][32] (U_v^T)
    float*  ck_lam = cw + 9437184;              // [2048]
    float* nw2   = cw + 9439232;
    __bf16* xb   = (__bf16*)nw2;                // 4096x1024 bf16
    __bf16* WqT  = (__bf16*)(nw2 + 2097152);    // 1024x1024 bf16 (transposed)
    __bf16* WkT  = (__bf16*)(nw2 + 2621440);
    __bf16* WvT  = (__bf16*)(nw2 + 3145728);
    __bf16* WoT  = (__bf16*)(nw2 + 3670016);
    __bf16* Wg2T = (__bf16*)(nw2 + 4194304);    // 1024x64 bf16
    __bf16* W96T = (__bf16*)(nw2 + 4227072);    // 128x1024 bf16 (padded)
    float* c96   = nw2 + 4292608;               // 4096x128 f32
    __bf16* lnob = (__bf16*)qb;                 // reuse qb

    dim3 blk(256);
    xcvt<<<2048, blk, 0, stream>>>(x, xb);
    wtrans<<<dim3(16, 16, 4), blk, 0, stream>>>(Wq, Wk, Wv, Wo, WqT, WkT, WvT, WoT,
                                                DD, DD);
    wtrans<<<dim3(16, 1, 1), blk, 0, stream>>>(Wg2, Wg2, Wg2, Wg2, Wg2T, Wg2T, Wg2T,
                                               Wg2T, HD, DD);
    wtrans96<<<128, blk, 0, stream>>>(Wgm, Wf, Wg1, W96T);
    // fused q,k,v + 96-col proj: 25 x-blocks = 3x8 col-tiles + 1 (mat 3, N=128)
    gemm_bt<<<dim3(25, 32), blk, 0, stream>>>(xb, WqT, WkT, WvT, W96T,
                                              qb, kb, vb, c96, RR, DD, DD);
    scal_prep<<<RR / 16, blk, 0, stream>>>(c96, lfb, csb, g1b);
    gemm_bt<<<dim3(8, 32), blk, 0, stream>>>(g1b, Wg2T, Wg2T, Wg2T, Wg2T,
                                             gatep, gatep, gatep, gatep, RR, DD, HD);
    chunk_prep<<<32 * NC, 64, 0, stream>>>(qb, kb, vb, lfb, csb,
                                           ck_mkh, ck_q, ck_kbT, ck_G, ck_uvT, ck_lam);
    chunk_scan<<<128, 64, 0, stream>>>(ck_mkh, ck_q, ck_kbT, ck_G, ck_uvT, ck_lam, obh);
    gate_ln_kernel<<<RR, blk, 0, stream>>>(obh, gatep, nw, lnob);
    gemm_bt<<<dim3(8, 32), blk, 0, stream>>>(lnob, WoT, WoT, WoT, WoT,
                                             out, out, out, out, RR, DD, DD);
}